// Round 12
// baseline (2272.721 us; speedup 1.0000x reference)
//
#include <hip/hip_runtime.h>
#include <cstdint>
#include <cstddef>

typedef __attribute__((ext_vector_type(8))) short short8;
typedef __attribute__((ext_vector_type(4))) float f32x4;
typedef __attribute__((ext_vector_type(2))) float f32x2;

#define NBLK 512        // edge-chunk blocks for hist/scatter (pow2)
#define NBLK_SHIFT 9

__device__ inline unsigned short f2bf(float f) {
  union { float f; unsigned int u; } x; x.f = f;
  unsigned int r = x.u + 0x7FFFu + ((x.u >> 16) & 1u);  // round-to-nearest-even
  return (unsigned short)(r >> 16);
}
__device__ inline float bf2f(unsigned short s) {
  union { unsigned int u; float f; } x; x.u = ((unsigned int)s) << 16;
  return x.f;
}

// ---------------- P1: per-block bucket histogram (LDS atomics only) ----------------
// blocks 0..2 transpose W1..W3 to bf16 Wt; every block reduces a slice of labels.

__global__ __launch_bounds__(256) void hist_kernel(const int* __restrict__ cols,
                                                   int* __restrict__ histG,
                                                   const int* __restrict__ labels,
                                                   float* __restrict__ pmsum,
                                                   const float* __restrict__ W1,
                                                   const float* __restrict__ W2,
                                                   const float* __restrict__ W3,
                                                   unsigned short* __restrict__ Wt1,
                                                   unsigned short* __restrict__ Wt2,
                                                   unsigned short* __restrict__ Wt3,
                                                   int E, int N, int NBUCK) {
  __shared__ int h[512];
  if (blockIdx.x < 3) {
    const float* W; unsigned short* Wt; int K;
    if (blockIdx.x == 0)      { W = W1; Wt = Wt1; K = 128; }
    else if (blockIdx.x == 1) { W = W2; Wt = Wt2; K = 64; }
    else                      { W = W3; Wt = Wt3; K = 64; }
    int total = K * 64;
    for (int i = threadIdx.x; i < total; i += 256) {
      int n = i / K, k = i - n * K;  // Wt[n][k] = W[k][n]
      Wt[i] = f2bf(W[k * 64 + n]);
    }
  }
  {
    int chunkL = (N + NBLK - 1) / NBLK;
    int ls = blockIdx.x * chunkL;
    int le = min(N, ls + chunkL);
    float v = 0.f;
    for (int i = ls + threadIdx.x; i < le; i += 256) v += (float)labels[i];
#pragma unroll
    for (int o = 32; o > 0; o >>= 1) v += __shfl_down(v, o);
    __shared__ float sl[4];
    if ((threadIdx.x & 63) == 0) sl[threadIdx.x >> 6] = v;
    __syncthreads();
    if (threadIdx.x == 0) {
      float t = sl[0] + sl[1] + sl[2] + sl[3];
      if (t != 0.f) atomicAdd(pmsum, t);
    }
  }
  for (int i = threadIdx.x; i < NBUCK; i += 256) h[i] = 0;
  __syncthreads();
  int chunk = (E + NBLK - 1) / NBLK;
  int s = blockIdx.x * chunk;
  int e = min(E, s + chunk);
  for (int i = s + threadIdx.x; i < e; i += 256) atomicAdd(&h[cols[i] >> 8], 1);
  __syncthreads();
  for (int i = threadIdx.x; i < NBUCK; i += 256)
    histG[blockIdx.x * NBUCK + i] = h[i];
}

// ---------------- P2: scan of NBUCK*NBLK counts, bucket-major logical order ----------------

__global__ __launch_bounds__(256) void scan_partials_t(const int* __restrict__ histG,
                                                       int* __restrict__ partials,
                                                       int total, int NBUCK) {
  int i = blockIdx.x * 256 + threadIdx.x;
  int v = 0;
  if (i < total) {
    int bucket = i >> NBLK_SHIFT, blk = i & (NBLK - 1);
    v = histG[blk * NBUCK + bucket];
  }
#pragma unroll
  for (int o = 32; o > 0; o >>= 1) v += __shfl_down(v, o);
  __shared__ int s[4];
  if ((threadIdx.x & 63) == 0) s[threadIdx.x >> 6] = v;
  __syncthreads();
  if (threadIdx.x == 0) partials[blockIdx.x] = s[0] + s[1] + s[2] + s[3];
}

__global__ __launch_bounds__(256) void scan_block(int* __restrict__ partials, int nb,
                                                  float* __restrict__ loss) {
  __shared__ int tmp[256];
  __shared__ int carry;
  int tid = threadIdx.x;
  if (tid == 0) { carry = 0; *loss = 0.f; }
  __syncthreads();
  for (int base = 0; base < nb; base += 256) {
    int i = base + tid;
    int v = (i < nb) ? partials[i] : 0;
    tmp[tid] = v;
    __syncthreads();
    int incl = v;
    for (int o = 1; o < 256; o <<= 1) {
      int t = (tid >= o) ? tmp[tid - o] : 0;
      __syncthreads();
      incl += t;
      tmp[tid] = incl;
      __syncthreads();
    }
    int total = tmp[255];
    int c = carry;
    if (i < nb) partials[i] = c + incl - v;  // exclusive
    __syncthreads();
    if (tid == 0) carry = c + total;
    __syncthreads();
  }
}

__global__ __launch_bounds__(256) void scan_final_t(const int* __restrict__ histG,
                                                    const int* __restrict__ partials,
                                                    int* __restrict__ scannedG,
                                                    int total, int NBUCK) {
  __shared__ int tmp[256];
  int tid = threadIdx.x;
  int i = blockIdx.x * 256 + tid;
  int bucket = i >> NBLK_SHIFT, blk = i & (NBLK - 1);
  int v = (i < total) ? histG[blk * NBUCK + bucket] : 0;
  tmp[tid] = v;
  __syncthreads();
  int incl = v;
  for (int o = 1; o < 256; o <<= 1) {
    int t = (tid >= o) ? tmp[tid - o] : 0;
    __syncthreads();
    incl += t;
    tmp[tid] = incl;
    __syncthreads();
  }
  if (i < total) scannedG[blk * NBUCK + bucket] = partials[blockIdx.x] + incl - v;
}

// ---------------- P3: bucket-partition scatter (LDS cursors, no global atomics) ----------------

__global__ __launch_bounds__(256) void scatter_kernel(const int* __restrict__ rows,
                                                      const int* __restrict__ cols,
                                                      const int* __restrict__ scannedG,
                                                      unsigned int* __restrict__ packed,
                                                      int E, int NBUCK) {
  __shared__ int cur[512];
  for (int i = threadIdx.x; i < NBUCK; i += 256)
    cur[i] = scannedG[blockIdx.x * NBUCK + i];
  __syncthreads();
  int chunk = (E + NBLK - 1) / NBLK;
  int s = blockIdx.x * chunk;
  int e = min(E, s + chunk);
  for (int i = s + threadIdx.x; i < e; i += 256) {
    int c = cols[i];
    int r = rows[i];
    int pos = atomicAdd(&cur[c >> 8], 1);
    packed[pos] = ((unsigned int)(c & 255) << 24) | (unsigned int)r;
  }
}

// ---------------- P4: per-bucket degree -> dinv (replaces csr_finalize) ----------------

__global__ __launch_bounds__(256) void dinv_kernel(const unsigned int* __restrict__ packed,
                                                   const int* __restrict__ scannedG,
                                                   float* __restrict__ dinv,
                                                   int N, int E, int NBUCK) {
  __shared__ int h[256];
  int b = blockIdx.x, tid = threadIdx.x;
  int base = scannedG[b];
  int end = (b + 1 < NBUCK) ? scannedG[b + 1] : E;
  h[tid] = 0;
  __syncthreads();
  for (int i = base + tid; i < end; i += 256) atomicAdd(&h[packed[i] >> 24], 1);
  __syncthreads();
  int node = b * 256 + tid;
  if (node < N) dinv[node] = rsqrtf((float)(h[tid] + 1));  // +1 self loop
}

// ---------------- MFMA GEMM: A_fp8[N,64] = (h[N,K] @ W[K,64]) * dinv[n] ----------------

template <int K, bool F32IN>
__global__ __launch_bounds__(256) void mfma_gemm(const void* __restrict__ hv,
                                                 const unsigned short* __restrict__ Wt,
                                                 const float* __restrict__ dinv,
                                                 unsigned char* __restrict__ out, int N) {
  __shared__ unsigned short tile[4][16 * 68];
  int w = threadIdx.x >> 6, lane = threadIdx.x & 63;
  int m = lane & 15, quad = lane >> 4;
  int m0 = blockIdx.x * 64 + w * 16;
  int rowA = m0 + m;
  bool rowOK = rowA < N;
  f32x4 acc[4] = {{0.f,0.f,0.f,0.f},{0.f,0.f,0.f,0.f},{0.f,0.f,0.f,0.f},{0.f,0.f,0.f,0.f}};
#pragma unroll
  for (int kc = 0; kc < K / 32; ++kc) {
    short8 a = {0, 0, 0, 0, 0, 0, 0, 0};
    if (rowOK) {
      if (F32IN) {
        const float* hp = (const float*)hv + (size_t)rowA * K + kc * 32 + quad * 8;
        float4 p0 = ((const float4*)hp)[0];
        float4 p1 = ((const float4*)hp)[1];
        a[0] = (short)f2bf(p0.x); a[1] = (short)f2bf(p0.y);
        a[2] = (short)f2bf(p0.z); a[3] = (short)f2bf(p0.w);
        a[4] = (short)f2bf(p1.x); a[5] = (short)f2bf(p1.y);
        a[6] = (short)f2bf(p1.z); a[7] = (short)f2bf(p1.w);
      } else {
        a = *(const short8*)((const unsigned short*)hv + (size_t)rowA * K + kc * 32 + quad * 8);
      }
    }
#pragma unroll
    for (int t = 0; t < 4; ++t) {
      short8 b = *(const short8*)(Wt + (size_t)(t * 16 + m) * K + kc * 32 + quad * 8);
      acc[t] = __builtin_amdgcn_mfma_f32_16x16x32_bf16(a, b, acc[t], 0, 0, 0);
    }
  }
  unsigned short* tw = tile[w];
#pragma unroll
  for (int r = 0; r < 4; ++r) {
    int row = quad * 4 + r;
    int gr = m0 + row;
    float dv = dinv[gr < N ? gr : 0];
#pragma unroll
    for (int t = 0; t < 4; ++t)
      tw[row * 68 + t * 16 + m] = f2bf(acc[t][r] * dv);
  }
#pragma unroll
  for (int p = 0; p < 4; ++p) {
    int row = p * 4 + (lane >> 4);
    int ch = lane & 15;  // 4-feature chunk
    int gr = m0 + row;
    if (gr < N) {
      uint2 v = *(const uint2*)(tw + row * 68 + ch * 4);
      float f0 = bf2f((unsigned short)(v.x & 0xFFFFu));
      float f1 = bf2f((unsigned short)(v.x >> 16));
      float f2 = bf2f((unsigned short)(v.y & 0xFFFFu));
      float f3 = bf2f((unsigned short)(v.y >> 16));
      int pk = 0;
      pk = __builtin_amdgcn_cvt_pk_fp8_f32(f0, f1, pk, false);
      pk = __builtin_amdgcn_cvt_pk_fp8_f32(f2, f3, pk, true);
      *(unsigned int*)(out + (size_t)gr * 64 + ch * 4) = (unsigned int)pk;
    }
  }
}

// ---------------- push-style LDS-accumulator aggregate + self loop + bias + ReLU ----------------
// one block per 256-node bucket; 512 threads; edges streamed from packed (no shfl
// in the dependent chain); fp32 LDS accumulators (stride 68 breaks bank aliasing);
// 4-edge unroll keeps 4 independent gathers in flight per wave.

__global__ __launch_bounds__(512) void aggregate_lds(const unsigned char* __restrict__ A8,
                                                     const unsigned int* __restrict__ packed,
                                                     const int* __restrict__ scannedG,
                                                     const float* __restrict__ dinv,
                                                     const float* __restrict__ bias,
                                                     unsigned short* __restrict__ out,
                                                     int N, int E, int NBUCK) {
  __shared__ float hacc[256 * 68];
  int tid = threadIdx.x;
  int b = blockIdx.x;
  int base = scannedG[b];
  int end = (b + 1 < NBUCK) ? scannedG[b + 1] : E;
  for (int i = tid; i < 256 * 68; i += 512) hacc[i] = 0.f;
  __syncthreads();
  int fi = tid & 7;       // 8B chunk of the 64B fp8 row
  int gid = tid >> 3;     // edge group 0..63
  for (int i = base + gid * 4; i < end; i += 64 * 4) {
    unsigned int p0 = 0, p1 = 0, p2 = 0, p3 = 0;
    int n_valid = end - i; if (n_valid > 4) n_valid = 4;
    p0 = packed[i];
    if (n_valid > 1) p1 = packed[i + 1];
    if (n_valid > 2) p2 = packed[i + 2];
    if (n_valid > 3) p3 = packed[i + 3];
    // issue all gathers (invalid ones read row 0 of p0's address space harmlessly? no—
    // guard with valid row: reuse p0 for invalid, adds discarded via n_valid checks below)
    uint2 v0, v1, v2, v3;
    v0 = *(const uint2*)(A8 + ((size_t)(p0 & 0xFFFFFFu) << 6) + fi * 8);
    v1 = *(const uint2*)(A8 + ((size_t)((n_valid > 1 ? p1 : p0) & 0xFFFFFFu) << 6) + fi * 8);
    v2 = *(const uint2*)(A8 + ((size_t)((n_valid > 2 ? p2 : p0) & 0xFFFFFFu) << 6) + fi * 8);
    v3 = *(const uint2*)(A8 + ((size_t)((n_valid > 3 ? p3 : p0) & 0xFFFFFFu) << 6) + fi * 8);
    {
      float* hp = &hacc[(p0 >> 24) * 68 + fi * 8];
      f32x2 d0 = __builtin_amdgcn_cvt_pk_f32_fp8((int)v0.x, false);
      f32x2 d1 = __builtin_amdgcn_cvt_pk_f32_fp8((int)v0.x, true);
      f32x2 d2 = __builtin_amdgcn_cvt_pk_f32_fp8((int)v0.y, false);
      f32x2 d3 = __builtin_amdgcn_cvt_pk_f32_fp8((int)v0.y, true);
      atomicAdd(hp + 0, d0[0]); atomicAdd(hp + 1, d0[1]);
      atomicAdd(hp + 2, d1[0]); atomicAdd(hp + 3, d1[1]);
      atomicAdd(hp + 4, d2[0]); atomicAdd(hp + 5, d2[1]);
      atomicAdd(hp + 6, d3[0]); atomicAdd(hp + 7, d3[1]);
    }
    if (n_valid > 1) {
      float* hp = &hacc[(p1 >> 24) * 68 + fi * 8];
      f32x2 d0 = __builtin_amdgcn_cvt_pk_f32_fp8((int)v1.x, false);
      f32x2 d1 = __builtin_amdgcn_cvt_pk_f32_fp8((int)v1.x, true);
      f32x2 d2 = __builtin_amdgcn_cvt_pk_f32_fp8((int)v1.y, false);
      f32x2 d3 = __builtin_amdgcn_cvt_pk_f32_fp8((int)v1.y, true);
      atomicAdd(hp + 0, d0[0]); atomicAdd(hp + 1, d0[1]);
      atomicAdd(hp + 2, d1[0]); atomicAdd(hp + 3, d1[1]);
      atomicAdd(hp + 4, d2[0]); atomicAdd(hp + 5, d2[1]);
      atomicAdd(hp + 6, d3[0]); atomicAdd(hp + 7, d3[1]);
    }
    if (n_valid > 2) {
      float* hp = &hacc[(p2 >> 24) * 68 + fi * 8];
      f32x2 d0 = __builtin_amdgcn_cvt_pk_f32_fp8((int)v2.x, false);
      f32x2 d1 = __builtin_amdgcn_cvt_pk_f32_fp8((int)v2.x, true);
      f32x2 d2 = __builtin_amdgcn_cvt_pk_f32_fp8((int)v2.y, false);
      f32x2 d3 = __builtin_amdgcn_cvt_pk_f32_fp8((int)v2.y, true);
      atomicAdd(hp + 0, d0[0]); atomicAdd(hp + 1, d0[1]);
      atomicAdd(hp + 2, d1[0]); atomicAdd(hp + 3, d1[1]);
      atomicAdd(hp + 4, d2[0]); atomicAdd(hp + 5, d2[1]);
      atomicAdd(hp + 6, d3[0]); atomicAdd(hp + 7, d3[1]);
    }
    if (n_valid > 3) {
      float* hp = &hacc[(p3 >> 24) * 68 + fi * 8];
      f32x2 d0 = __builtin_amdgcn_cvt_pk_f32_fp8((int)v3.x, false);
      f32x2 d1 = __builtin_amdgcn_cvt_pk_f32_fp8((int)v3.x, true);
      f32x2 d2 = __builtin_amdgcn_cvt_pk_f32_fp8((int)v3.y, false);
      f32x2 d3 = __builtin_amdgcn_cvt_pk_f32_fp8((int)v3.y, true);
      atomicAdd(hp + 0, d0[0]); atomicAdd(hp + 1, d0[1]);
      atomicAdd(hp + 2, d1[0]); atomicAdd(hp + 3, d1[1]);
      atomicAdd(hp + 4, d2[0]); atomicAdd(hp + 5, d2[1]);
      atomicAdd(hp + 6, d3[0]); atomicAdd(hp + 7, d3[1]);
    }
  }
  __syncthreads();
  // epilogue: thread t -> node n = t>>1, feature half = (t&1)*32
  int n = tid >> 1;
  int half = (tid & 1) * 32;
  int c = b * 256 + n;
  if (c < N) {
    float dc = dinv[c];
    const unsigned char* sp = A8 + (size_t)c * 64 + half;
    unsigned short o16[32];
#pragma unroll
    for (int u = 0; u < 8; ++u) {  // 8 dwords = 32 fp8 self feats
      unsigned int sw = ((const unsigned int*)sp)[u];
      f32x2 s0 = __builtin_amdgcn_cvt_pk_f32_fp8((int)sw, false);
      f32x2 s1 = __builtin_amdgcn_cvt_pk_f32_fp8((int)sw, true);
      float sf[4] = {s0[0], s0[1], s1[0], s1[1]};
#pragma unroll
      for (int q = 0; q < 4; ++q) {
        int f = u * 4 + q;
        float v = fmaf(hacc[n * 68 + half + f] + sf[q], dc, bias[half + f]);
        o16[f] = f2bf(v > 0.f ? v : 0.f);
      }
    }
#pragma unroll
    for (int u = 0; u < 4; ++u)
      ((short8*)(out + (size_t)c * 64 + half))[u] = *(short8*)&o16[u * 8];
  }
}

// ---------------- MLP head + sigmoid + weighted BCE loss (bf16 h) ----------------

__global__ __launch_bounds__(256) void head_loss_kernel(const unsigned short* __restrict__ h,
                                                        const float* __restrict__ lW1,
                                                        const float* __restrict__ lb1,
                                                        const float* __restrict__ lW2,
                                                        const float* __restrict__ lb2,
                                                        const int* __restrict__ labels,
                                                        const float* __restrict__ pmsum,
                                                        float* __restrict__ p,
                                                        float* __restrict__ loss, int N) {
  int n = blockIdx.x * 256 + threadIdx.x;
  float contrib = 0.f;
  if (n < N) {
    float acc[8];
#pragma unroll
    for (int j = 0; j < 8; ++j) acc[j] = lb1[j];
    const unsigned short* hr = h + (size_t)n * 64;
#pragma unroll
    for (int ch = 0; ch < 8; ++ch) {
      short8 hv8 = ((const short8*)hr)[ch];
#pragma unroll
      for (int q = 0; q < 8; ++q) {
        float v = bf2f((unsigned short)hv8[q]);
        int k = ch * 8 + q;
#pragma unroll
        for (int j = 0; j < 8; ++j) acc[j] = fmaf(v, lW1[k * 8 + j], acc[j]);
      }
    }
    float s = lb2[0];
#pragma unroll
    for (int j = 0; j < 8; ++j) {
      float a = acc[j] > 0.f ? acc[j] : 0.f;
      s = fmaf(a, lW2[j], s);
    }
    float pv = 1.0f / (1.0f + expf(-s));
    p[n] = pv;
    float pm = *pmsum / (float)N;
    float y = (float)labels[n];
    float w = y * (1.f - pm) + (1.f - y) * pm;
    float pc = fminf(fmaxf(pv, 1e-7f), 1.f - 1e-7f);
    float bce = -(y * logf(pc) + (1.f - y) * logf(1.f - pc));
    contrib = w * bce / (float)N;
  }
#pragma unroll
  for (int o = 32; o > 0; o >>= 1) contrib += __shfl_down(contrib, o);
  __shared__ float sh[4];
  int lane = threadIdx.x & 63, w = threadIdx.x >> 6;
  if (lane == 0) sh[w] = contrib;
  __syncthreads();
  if (threadIdx.x == 0) atomicAdd(loss, sh[0] + sh[1] + sh[2] + sh[3]);
}

// ---------------- launch ----------------

extern "C" void kernel_launch(void* const* d_in, const int* in_sizes, int n_in,
                              void* d_out, int out_size, void* d_ws, size_t ws_size,
                              hipStream_t stream) {
  const float* x      = (const float*)d_in[0];
  const int*   ei     = (const int*)d_in[1];
  const int*   labels = (const int*)d_in[2];
  const float* W1 = (const float*)d_in[3];
  const float* b1 = (const float*)d_in[4];
  const float* W2 = (const float*)d_in[5];
  const float* b2 = (const float*)d_in[6];
  const float* W3 = (const float*)d_in[7];
  const float* b3 = (const float*)d_in[8];
  const float* lW1 = (const float*)d_in[9];
  const float* lb1 = (const float*)d_in[10];
  const float* lW2 = (const float*)d_in[11];
  const float* lb2 = (const float*)d_in[12];

  int N = in_sizes[2];            // labels: [N,1]
  int E = in_sizes[1] / 2;        // edge_index: [2,E]
  const int* rows = ei;           // sources
  const int* cols = ei + E;       // targets (aggregation)

  int nb = (N + 255) / 256;
  int Npad = (N + 63) & ~63;
  int NBUCK = (N + 255) >> 8;               // 256-node buckets
  int totalH = NBUCK * NBLK;                // histogram entries
  int nb2 = (totalH + 255) / 256;

  // workspace layout
  char* ws = (char*)d_ws;
  unsigned char*  A8  = (unsigned char*)ws;             // (h@W)*dinv  Npad*64 fp8
  unsigned short* H   = (unsigned short*)(ws + (size_t)Npad * 64);  // hidden Npad*64 bf16
  unsigned short* Wt1 = H + (size_t)Npad * 64;          // 64*128
  unsigned short* Wt2 = Wt1 + 64 * 128;                 // 64*64
  unsigned short* Wt3 = Wt2 + 64 * 64;                  // 64*64
  float* dinv     = (float*)(Wt3 + 64 * 64);            // N
  int*   histG    = (int*)(dinv + N);                   // NBLK*NBUCK
  int*   scanned  = histG + totalH;                     // NBLK*NBUCK
  unsigned int* packed = (unsigned int*)(scanned + totalH);  // E
  int*   partials = (int*)(packed + E);                 // nb2
  float* pmsum    = (float*)(partials + nb2);           // 1

  float* loss = (float*)d_out;
  float* p    = (float*)d_out + 1;

  int gemmBlocks = Npad / 64;

  // ---- atomic-free CSR-lite build (bucketed edge lists only) ----
  hipMemsetAsync(pmsum, 0, sizeof(float), stream);
  hist_kernel<<<NBLK, 256, 0, stream>>>(cols, histG, labels, pmsum,
                                        W1, W2, W3, Wt1, Wt2, Wt3, E, N, NBUCK);
  scan_partials_t<<<nb2, 256, 0, stream>>>(histG, partials, totalH, NBUCK);
  scan_block<<<1, 256, 0, stream>>>(partials, nb2, loss);  // also zeroes loss
  scan_final_t<<<nb2, 256, 0, stream>>>(histG, partials, scanned, totalH, NBUCK);
  scatter_kernel<<<NBLK, 256, 0, stream>>>(rows, cols, scanned, packed, E, NBUCK);
  dinv_kernel<<<NBUCK, 256, 0, stream>>>(packed, scanned, dinv, N, E, NBUCK);

  // ---- layer 1 (K=128, fp32 x converted in-flight) ----
  mfma_gemm<128, true><<<gemmBlocks, 256, 0, stream>>>(x, Wt1, dinv, A8, N);
  aggregate_lds<<<NBUCK, 512, 0, stream>>>(A8, packed, scanned, dinv, b1, H, N, E, NBUCK);

  // ---- layer 2 (K=64, bf16) ----
  mfma_gemm<64, false><<<gemmBlocks, 256, 0, stream>>>(H, Wt2, dinv, A8, N);
  aggregate_lds<<<NBUCK, 512, 0, stream>>>(A8, packed, scanned, dinv, b2, H, N, E, NBUCK);

  // ---- layer 3 (K=64, bf16) ----
  mfma_gemm<64, false><<<gemmBlocks, 256, 0, stream>>>(H, Wt3, dinv, A8, N);
  aggregate_lds<<<NBUCK, 512, 0, stream>>>(A8, packed, scanned, dinv, b3, H, N, E, NBUCK);

  // ---- head + loss ----
  head_loss_kernel<<<nb, 256, 0, stream>>>(H, lW1, lb1, lW2, lb2, labels, pmsum, p, loss, N);
}

// Round 13
// 311.524 us; speedup vs baseline: 7.2955x; 7.2955x over previous
//
#include <hip/hip_runtime.h>
#include <cstdint>
#include <cstddef>

typedef __attribute__((ext_vector_type(8))) short short8;
typedef __attribute__((ext_vector_type(4))) float f32x4;
typedef __attribute__((ext_vector_type(2))) float f32x2;

#define NBLK 512        // edge-chunk blocks for hist/scatter (pow2)
#define NBLK_SHIFT 9

__device__ inline unsigned short f2bf(float f) {
  union { float f; unsigned int u; } x; x.f = f;
  unsigned int r = x.u + 0x7FFFu + ((x.u >> 16) & 1u);  // round-to-nearest-even
  return (unsigned short)(r >> 16);
}
__device__ inline float bf2f(unsigned short s) {
  union { unsigned int u; float f; } x; x.u = ((unsigned int)s) << 16;
  return x.f;
}

// ---------------- P1: per-block bucket histogram (LDS atomics only) ----------------
// blocks 0..2 transpose W1..W3 to bf16 Wt; every block reduces a slice of labels.

__global__ __launch_bounds__(256) void hist_kernel(const int* __restrict__ cols,
                                                   int* __restrict__ histG,
                                                   const int* __restrict__ labels,
                                                   float* __restrict__ pmsum,
                                                   const float* __restrict__ W1,
                                                   const float* __restrict__ W2,
                                                   const float* __restrict__ W3,
                                                   unsigned short* __restrict__ Wt1,
                                                   unsigned short* __restrict__ Wt2,
                                                   unsigned short* __restrict__ Wt3,
                                                   int E, int N, int NBUCK) {
  __shared__ int h[512];
  if (blockIdx.x < 3) {
    const float* W; unsigned short* Wt; int K;
    if (blockIdx.x == 0)      { W = W1; Wt = Wt1; K = 128; }
    else if (blockIdx.x == 1) { W = W2; Wt = Wt2; K = 64; }
    else                      { W = W3; Wt = Wt3; K = 64; }
    int total = K * 64;
    for (int i = threadIdx.x; i < total; i += 256) {
      int n = i / K, k = i - n * K;  // Wt[n][k] = W[k][n]
      Wt[i] = f2bf(W[k * 64 + n]);
    }
  }
  {
    int chunkL = (N + NBLK - 1) / NBLK;
    int ls = blockIdx.x * chunkL;
    int le = min(N, ls + chunkL);
    float v = 0.f;
    for (int i = ls + threadIdx.x; i < le; i += 256) v += (float)labels[i];
#pragma unroll
    for (int o = 32; o > 0; o >>= 1) v += __shfl_down(v, o);
    __shared__ float sl[4];
    if ((threadIdx.x & 63) == 0) sl[threadIdx.x >> 6] = v;
    __syncthreads();
    if (threadIdx.x == 0) {
      float t = sl[0] + sl[1] + sl[2] + sl[3];
      if (t != 0.f) atomicAdd(pmsum, t);
    }
  }
  for (int i = threadIdx.x; i < NBUCK; i += 256) h[i] = 0;
  __syncthreads();
  int chunk = (E + NBLK - 1) / NBLK;
  int s = blockIdx.x * chunk;
  int e = min(E, s + chunk);
  for (int i = s + threadIdx.x; i < e; i += 256) atomicAdd(&h[cols[i] >> 8], 1);
  __syncthreads();
  for (int i = threadIdx.x; i < NBUCK; i += 256)
    histG[blockIdx.x * NBUCK + i] = h[i];
}

// ---------------- P2: scan of NBUCK*NBLK counts, bucket-major logical order ----------------

__global__ __launch_bounds__(256) void scan_partials_t(const int* __restrict__ histG,
                                                       int* __restrict__ partials,
                                                       int total, int NBUCK) {
  int i = blockIdx.x * 256 + threadIdx.x;
  int v = 0;
  if (i < total) {
    int bucket = i >> NBLK_SHIFT, blk = i & (NBLK - 1);
    v = histG[blk * NBUCK + bucket];
  }
#pragma unroll
  for (int o = 32; o > 0; o >>= 1) v += __shfl_down(v, o);
  __shared__ int s[4];
  if ((threadIdx.x & 63) == 0) s[threadIdx.x >> 6] = v;
  __syncthreads();
  if (threadIdx.x == 0) partials[blockIdx.x] = s[0] + s[1] + s[2] + s[3];
}

__global__ __launch_bounds__(256) void scan_block(int* __restrict__ partials, int nb,
                                                  float* __restrict__ loss) {
  __shared__ int tmp[256];
  __shared__ int carry;
  int tid = threadIdx.x;
  if (tid == 0) { carry = 0; *loss = 0.f; }
  __syncthreads();
  for (int base = 0; base < nb; base += 256) {
    int i = base + tid;
    int v = (i < nb) ? partials[i] : 0;
    tmp[tid] = v;
    __syncthreads();
    int incl = v;
    for (int o = 1; o < 256; o <<= 1) {
      int t = (tid >= o) ? tmp[tid - o] : 0;
      __syncthreads();
      incl += t;
      tmp[tid] = incl;
      __syncthreads();
    }
    int total = tmp[255];
    int c = carry;
    if (i < nb) partials[i] = c + incl - v;  // exclusive
    __syncthreads();
    if (tid == 0) carry = c + total;
    __syncthreads();
  }
}

__global__ __launch_bounds__(256) void scan_final_t(const int* __restrict__ histG,
                                                    const int* __restrict__ partials,
                                                    int* __restrict__ scannedG,
                                                    int total, int NBUCK) {
  __shared__ int tmp[256];
  int tid = threadIdx.x;
  int i = blockIdx.x * 256 + tid;
  int bucket = i >> NBLK_SHIFT, blk = i & (NBLK - 1);
  int v = (i < total) ? histG[blk * NBUCK + bucket] : 0;
  tmp[tid] = v;
  __syncthreads();
  int incl = v;
  for (int o = 1; o < 256; o <<= 1) {
    int t = (tid >= o) ? tmp[tid - o] : 0;
    __syncthreads();
    incl += t;
    tmp[tid] = incl;
    __syncthreads();
  }
  if (i < total) scannedG[blk * NBUCK + bucket] = partials[blockIdx.x] + incl - v;
}

// ---------------- P3: bucket-partition scatter (LDS cursors, no global atomics) ----------------

__global__ __launch_bounds__(256) void scatter_kernel(const int* __restrict__ rows,
                                                      const int* __restrict__ cols,
                                                      const int* __restrict__ scannedG,
                                                      unsigned int* __restrict__ packed,
                                                      int E, int NBUCK) {
  __shared__ int cur[512];
  for (int i = threadIdx.x; i < NBUCK; i += 256)
    cur[i] = scannedG[blockIdx.x * NBUCK + i];
  __syncthreads();
  int chunk = (E + NBLK - 1) / NBLK;
  int s = blockIdx.x * chunk;
  int e = min(E, s + chunk);
  for (int i = s + threadIdx.x; i < e; i += 256) {
    int c = cols[i];
    int r = rows[i];
    int pos = atomicAdd(&cur[c >> 8], 1);
    packed[pos] = ((unsigned int)(c & 255) << 24) | (unsigned int)r;
  }
}

// ---------------- P4: per-bucket CSR finalize (1024 threads/block) ----------------

__global__ __launch_bounds__(1024) void csr_finalize(const unsigned int* __restrict__ packed,
                                                     const int* __restrict__ scannedG,
                                                     int* __restrict__ sorted_src,
                                                     int* __restrict__ offsets,
                                                     float* __restrict__ dinv,
                                                     int N, int E, int NBUCK) {
  __shared__ int h[256];
  __shared__ int tmp[256];
  __shared__ int cur[256];
  int b = blockIdx.x;
  int tid = threadIdx.x;
  int base = scannedG[b];
  int end = (b + 1 < NBUCK) ? scannedG[b + 1] : E;
  if (tid < 256) h[tid] = 0;
  __syncthreads();
  for (int i = base + tid; i < end; i += 1024)
    atomicAdd(&h[packed[i] >> 24], 1);
  __syncthreads();
  if (tid < 256) {
    int v = h[tid];
    tmp[tid] = v;
  }
  __syncthreads();
  if (tid < 256) {
    int v = h[tid];
    int incl = v;
    for (int o = 1; o < 256; o <<= 1) {
      int t = (tid >= o) ? tmp[tid - o] : 0;
      __syncthreads();
      incl += t;
      tmp[tid] = incl;
      __syncthreads();
    }
    int excl = incl - v;
    int node = b * 256 + tid;
    if (node < N) {
      offsets[node] = base + excl;
      dinv[node] = rsqrtf((float)(v + 1));  // +1 self loop
    }
    cur[tid] = base + excl;
    if (b == NBUCK - 1 && tid == 0) offsets[N] = E;
  } else {
    for (int o = 1; o < 256; o <<= 1) { __syncthreads(); __syncthreads(); }
  }
  __syncthreads();
  for (int i = base + tid; i < end; i += 1024) {
    unsigned int p = packed[i];
    int pos = atomicAdd(&cur[p >> 24], 1);
    sorted_src[pos] = (int)(p & 0xFFFFFFu);
  }
}

// ---------------- MFMA GEMM: A_fp8[N,64] = (h[N,K] @ W[K,64]) * dinv[n] ----------------

template <int K, bool F32IN>
__global__ __launch_bounds__(256) void mfma_gemm(const void* __restrict__ hv,
                                                 const unsigned short* __restrict__ Wt,
                                                 const float* __restrict__ dinv,
                                                 unsigned char* __restrict__ out, int N) {
  __shared__ unsigned short tile[4][16 * 68];
  int w = threadIdx.x >> 6, lane = threadIdx.x & 63;
  int m = lane & 15, quad = lane >> 4;
  int m0 = blockIdx.x * 64 + w * 16;
  int rowA = m0 + m;
  bool rowOK = rowA < N;
  f32x4 acc[4] = {{0.f,0.f,0.f,0.f},{0.f,0.f,0.f,0.f},{0.f,0.f,0.f,0.f},{0.f,0.f,0.f,0.f}};
#pragma unroll
  for (int kc = 0; kc < K / 32; ++kc) {
    short8 a = {0, 0, 0, 0, 0, 0, 0, 0};
    if (rowOK) {
      if (F32IN) {
        const float* hp = (const float*)hv + (size_t)rowA * K + kc * 32 + quad * 8;
        float4 p0 = ((const float4*)hp)[0];
        float4 p1 = ((const float4*)hp)[1];
        a[0] = (short)f2bf(p0.x); a[1] = (short)f2bf(p0.y);
        a[2] = (short)f2bf(p0.z); a[3] = (short)f2bf(p0.w);
        a[4] = (short)f2bf(p1.x); a[5] = (short)f2bf(p1.y);
        a[6] = (short)f2bf(p1.z); a[7] = (short)f2bf(p1.w);
      } else {
        a = *(const short8*)((const unsigned short*)hv + (size_t)rowA * K + kc * 32 + quad * 8);
      }
    }
#pragma unroll
    for (int t = 0; t < 4; ++t) {
      short8 b = *(const short8*)(Wt + (size_t)(t * 16 + m) * K + kc * 32 + quad * 8);
      acc[t] = __builtin_amdgcn_mfma_f32_16x16x32_bf16(a, b, acc[t], 0, 0, 0);
    }
  }
  unsigned short* tw = tile[w];
#pragma unroll
  for (int r = 0; r < 4; ++r) {
    int row = quad * 4 + r;
    int gr = m0 + row;
    float dv = dinv[gr < N ? gr : 0];
#pragma unroll
    for (int t = 0; t < 4; ++t)
      tw[row * 68 + t * 16 + m] = f2bf(acc[t][r] * dv);
  }
#pragma unroll
  for (int p = 0; p < 4; ++p) {
    int row = p * 4 + (lane >> 4);
    int ch = lane & 15;  // 4-feature chunk
    int gr = m0 + row;
    if (gr < N) {
      uint2 v = *(const uint2*)(tw + row * 68 + ch * 4);
      float f0 = bf2f((unsigned short)(v.x & 0xFFFFu));
      float f1 = bf2f((unsigned short)(v.x >> 16));
      float f2 = bf2f((unsigned short)(v.y & 0xFFFFu));
      float f3 = bf2f((unsigned short)(v.y >> 16));
      int pk = 0;
      pk = __builtin_amdgcn_cvt_pk_fp8_f32(f0, f1, pk, false);
      pk = __builtin_amdgcn_cvt_pk_fp8_f32(f2, f3, pk, true);
      *(unsigned int*)(out + (size_t)gr * 64 + ch * 4) = (unsigned int)pk;
    }
  }
}

// ---------------- fused gather-aggregate + self loop + bias + ReLU ----------------
// A fp8 (64B rows). TWO nodes per wave (32 lanes each): 4 edge-groups x 8 lanes,
// 8B/lane chunk. Avg degree ~16 -> 4 gathers in flight per half (8/wave, 4x the
// single-node layout). fp32 accumulate; out H is bf16.

__global__ __launch_bounds__(256) void aggregate(const unsigned char* __restrict__ A8,
                                                 const int* __restrict__ offsets,
                                                 const int* __restrict__ sorted_src,
                                                 const float* __restrict__ dinv,
                                                 const float* __restrict__ bias,
                                                 unsigned short* __restrict__ out, int N) {
  int c = blockIdx.x * 8 + (threadIdx.x >> 5);   // one node per 32-lane half
  if (c >= N) return;
  int l = threadIdx.x & 31;
  int halfbase = threadIdx.x & 32;   // 0 or 32: this half's base lane in the wave
  int g = l >> 3;                    // edge sub-slot 0..3
  int fi = l & 7;                    // 8B chunk (8 feats) of the 64B row
  int s = offsets[c], e = offsets[c + 1];
  float dc = dinv[c];
  uint2 svr = *(const uint2*)(A8 + (size_t)c * 64 + fi * 8);
  f32x2 a0 = {0.f, 0.f}, a1 = {0.f, 0.f}, a2 = {0.f, 0.f}, a3 = {0.f, 0.f};
  for (int base = s; base < e; base += 32) {
    int idx = base + l;
    int r = (idx < e) ? sorted_src[idx] : 0;
    int cnt = e - base; if (cnt > 32) cnt = 32;
    int rj[8];
#pragma unroll
    for (int t = 0; t < 8; ++t) rj[t] = __shfl(r, halfbase + t * 4 + g);
#pragma unroll
    for (int t = 0; t < 8; ++t) {
      if (t * 4 + g < cnt) {
        uint2 v = *(const uint2*)(A8 + ((size_t)(unsigned int)rj[t] << 6) + fi * 8);
        a0 += __builtin_amdgcn_cvt_pk_f32_fp8((int)v.x, false);
        a1 += __builtin_amdgcn_cvt_pk_f32_fp8((int)v.x, true);
        a2 += __builtin_amdgcn_cvt_pk_f32_fp8((int)v.y, false);
        a3 += __builtin_amdgcn_cvt_pk_f32_fp8((int)v.y, true);
      }
    }
  }
  float acc[8] = {a0[0], a0[1], a1[0], a1[1], a2[0], a2[1], a3[0], a3[1]};
#pragma unroll
  for (int q = 0; q < 8; ++q) {          // reduce the 4 groups (stay within the half)
    acc[q] += __shfl_xor(acc[q], 8);
    acc[q] += __shfl_xor(acc[q], 16);
  }
  if (g == 0) {                          // lanes fi=0..7 of each half
    f32x2 s0 = __builtin_amdgcn_cvt_pk_f32_fp8((int)svr.x, false);
    f32x2 s1 = __builtin_amdgcn_cvt_pk_f32_fp8((int)svr.x, true);
    f32x2 s2 = __builtin_amdgcn_cvt_pk_f32_fp8((int)svr.y, false);
    f32x2 s3 = __builtin_amdgcn_cvt_pk_f32_fp8((int)svr.y, true);
    float sf[8] = {s0[0], s0[1], s1[0], s1[1], s2[0], s2[1], s3[0], s3[1]};
    short8 ov;
#pragma unroll
    for (int q = 0; q < 8; ++q) {
      float v = fmaf(acc[q] + sf[q], dc, bias[fi * 8 + q]);
      ov[q] = (short)f2bf(v > 0.f ? v : 0.f);
    }
    *(short8*)(out + (size_t)c * 64 + fi * 8) = ov;
  }
}

// ---------------- MLP head + sigmoid + weighted BCE loss (bf16 h) ----------------

__global__ __launch_bounds__(256) void head_loss_kernel(const unsigned short* __restrict__ h,
                                                        const float* __restrict__ lW1,
                                                        const float* __restrict__ lb1,
                                                        const float* __restrict__ lW2,
                                                        const float* __restrict__ lb2,
                                                        const int* __restrict__ labels,
                                                        const float* __restrict__ pmsum,
                                                        float* __restrict__ p,
                                                        float* __restrict__ loss, int N) {
  int n = blockIdx.x * 256 + threadIdx.x;
  float contrib = 0.f;
  if (n < N) {
    float acc[8];
#pragma unroll
    for (int j = 0; j < 8; ++j) acc[j] = lb1[j];
    const unsigned short* hr = h + (size_t)n * 64;
#pragma unroll
    for (int ch = 0; ch < 8; ++ch) {
      short8 hv8 = ((const short8*)hr)[ch];
#pragma unroll
      for (int q = 0; q < 8; ++q) {
        float v = bf2f((unsigned short)hv8[q]);
        int k = ch * 8 + q;
#pragma unroll
        for (int j = 0; j < 8; ++j) acc[j] = fmaf(v, lW1[k * 8 + j], acc[j]);
      }
    }
    float s = lb2[0];
#pragma unroll
    for (int j = 0; j < 8; ++j) {
      float a = acc[j] > 0.f ? acc[j] : 0.f;
      s = fmaf(a, lW2[j], s);
    }
    float pv = 1.0f / (1.0f + expf(-s));
    p[n] = pv;
    float pm = *pmsum / (float)N;
    float y = (float)labels[n];
    float w = y * (1.f - pm) + (1.f - y) * pm;
    float pc = fminf(fmaxf(pv, 1e-7f), 1.f - 1e-7f);
    float bce = -(y * logf(pc) + (1.f - y) * logf(1.f - pc));
    contrib = w * bce / (float)N;
  }
#pragma unroll
  for (int o = 32; o > 0; o >>= 1) contrib += __shfl_down(contrib, o);
  __shared__ float sh[4];
  int lane = threadIdx.x & 63, w = threadIdx.x >> 6;
  if (lane == 0) sh[w] = contrib;
  __syncthreads();
  if (threadIdx.x == 0) atomicAdd(loss, sh[0] + sh[1] + sh[2] + sh[3]);
}

// ---------------- launch ----------------

extern "C" void kernel_launch(void* const* d_in, const int* in_sizes, int n_in,
                              void* d_out, int out_size, void* d_ws, size_t ws_size,
                              hipStream_t stream) {
  const float* x      = (const float*)d_in[0];
  const int*   ei     = (const int*)d_in[1];
  const int*   labels = (const int*)d_in[2];
  const float* W1 = (const float*)d_in[3];
  const float* b1 = (const float*)d_in[4];
  const float* W2 = (const float*)d_in[5];
  const float* b2 = (const float*)d_in[6];
  const float* W3 = (const float*)d_in[7];
  const float* b3 = (const float*)d_in[8];
  const float* lW1 = (const float*)d_in[9];
  const float* lb1 = (const float*)d_in[10];
  const float* lW2 = (const float*)d_in[11];
  const float* lb2 = (const float*)d_in[12];

  int N = in_sizes[2];            // labels: [N,1]
  int E = in_sizes[1] / 2;        // edge_index: [2,E]
  const int* rows = ei;           // sources
  const int* cols = ei + E;       // targets (aggregation)

  int nb = (N + 255) / 256;
  int Npad = (N + 63) & ~63;
  int NBUCK = (N + 255) >> 8;               // 256-node buckets
  int totalH = NBUCK * NBLK;                // histogram entries
  int nb2 = (totalH + 255) / 256;

  // workspace layout
  char* ws = (char*)d_ws;
  unsigned char*  A8  = (unsigned char*)ws;             // (h@W)*dinv  Npad*64 fp8
  unsigned short* H   = (unsigned short*)(ws + (size_t)Npad * 64);  // hidden Npad*64 bf16
  unsigned short* Wt1 = H + (size_t)Npad * 64;          // 64*128
  unsigned short* Wt2 = Wt1 + 64 * 128;                 // 64*64
  unsigned short* Wt3 = Wt2 + 64 * 64;                  // 64*64
  float* dinv     = (float*)(Wt3 + 64 * 64);            // N
  int*   offsets  = (int*)(dinv + N);                   // N+1
  int*   histG    = offsets + N + 1;                    // NBLK*NBUCK
  int*   scanned  = histG + totalH;                     // NBLK*NBUCK
  unsigned int* packed = (unsigned int*)(scanned + totalH);  // E
  int*   sorted   = (int*)(packed + E);                 // E
  int*   partials = sorted + E;                         // nb2
  float* pmsum    = (float*)(partials + nb2);           // 1

  float* loss = (float*)d_out;
  float* p    = (float*)d_out + 1;

  int gemmBlocks = Npad / 64;
  int aggBlocks  = (N + 7) / 8;

  // ---- atomic-free CSR build (+ Wt transpose & label-sum folded into hist) ----
  hipMemsetAsync(pmsum, 0, sizeof(float), stream);
  hist_kernel<<<NBLK, 256, 0, stream>>>(cols, histG, labels, pmsum,
                                        W1, W2, W3, Wt1, Wt2, Wt3, E, N, NBUCK);
  scan_partials_t<<<nb2, 256, 0, stream>>>(histG, partials, totalH, NBUCK);
  scan_block<<<1, 256, 0, stream>>>(partials, nb2, loss);  // also zeroes loss
  scan_final_t<<<nb2, 256, 0, stream>>>(histG, partials, scanned, totalH, NBUCK);
  scatter_kernel<<<NBLK, 256, 0, stream>>>(rows, cols, scanned, packed, E, NBUCK);
  csr_finalize<<<NBUCK, 1024, 0, stream>>>(packed, scanned, sorted, offsets, dinv, N, E, NBUCK);

  // ---- layer 1 (K=128, fp32 x converted in-flight) ----
  mfma_gemm<128, true><<<gemmBlocks, 256, 0, stream>>>(x, Wt1, dinv, A8, N);
  aggregate<<<aggBlocks, 256, 0, stream>>>(A8, offsets, sorted, dinv, b1, H, N);

  // ---- layer 2 (K=64, bf16) ----
  mfma_gemm<64, false><<<gemmBlocks, 256, 0, stream>>>(H, Wt2, dinv, A8, N);
  aggregate<<<aggBlocks, 256, 0, stream>>>(A8, offsets, sorted, dinv, b2, H, N);

  // ---- layer 3 (K=64, bf16) ----
  mfma_gemm<64, false><<<gemmBlocks, 256, 0, stream>>>(H, Wt3, dinv, A8, N);
  aggregate<<<aggBlocks, 256, 0, stream>>>(A8, offsets, sorted, dinv, b3, H, N);

  // ---- head + loss ----
  head_loss_kernel<<<nb, 256, 0, stream>>>(H, lW1, lb1, lW2, lb2, labels, pmsum, p, loss, N);
}

// Round 14
// 308.094 us; speedup vs baseline: 7.3767x; 1.0111x over previous
//
#include <hip/hip_runtime.h>
#include <cstdint>
#include <cstddef>

typedef __attribute__((ext_vector_type(8))) short short8;
typedef __attribute__((ext_vector_type(4))) float f32x4;
typedef __attribute__((ext_vector_type(2))) float f32x2;

#define NBLK 512        // edge-chunk blocks for hist/scatter (pow2)
#define NBLK_SHIFT 9

__device__ inline unsigned short f2bf(float f) {
  union { float f; unsigned int u; } x; x.f = f;
  unsigned int r = x.u + 0x7FFFu + ((x.u >> 16) & 1u);  // round-to-nearest-even
  return (unsigned short)(r >> 16);
}
__device__ inline float bf2f(unsigned short s) {
  union { unsigned int u; float f; } x; x.u = ((unsigned int)s) << 16;
  return x.f;
}

// ---------------- P1: per-block bucket histogram (LDS atomics only) ----------------
// blocks 0..2 transpose W1..W3 to bf16 Wt; every block reduces a slice of labels.

__global__ __launch_bounds__(256) void hist_kernel(const int* __restrict__ cols,
                                                   int* __restrict__ histG,
                                                   const int* __restrict__ labels,
                                                   float* __restrict__ pmsum,
                                                   const float* __restrict__ W1,
                                                   const float* __restrict__ W2,
                                                   const float* __restrict__ W3,
                                                   unsigned short* __restrict__ Wt1,
                                                   unsigned short* __restrict__ Wt2,
                                                   unsigned short* __restrict__ Wt3,
                                                   int E, int N, int NBUCK) {
  __shared__ int h[512];
  if (blockIdx.x < 3) {
    const float* W; unsigned short* Wt; int K;
    if (blockIdx.x == 0)      { W = W1; Wt = Wt1; K = 128; }
    else if (blockIdx.x == 1) { W = W2; Wt = Wt2; K = 64; }
    else                      { W = W3; Wt = Wt3; K = 64; }
    int total = K * 64;
    for (int i = threadIdx.x; i < total; i += 256) {
      int n = i / K, k = i - n * K;  // Wt[n][k] = W[k][n]
      Wt[i] = f2bf(W[k * 64 + n]);
    }
  }
  {
    int chunkL = (N + NBLK - 1) / NBLK;
    int ls = blockIdx.x * chunkL;
    int le = min(N, ls + chunkL);
    float v = 0.f;
    for (int i = ls + threadIdx.x; i < le; i += 256) v += (float)labels[i];
#pragma unroll
    for (int o = 32; o > 0; o >>= 1) v += __shfl_down(v, o);
    __shared__ float sl[4];
    if ((threadIdx.x & 63) == 0) sl[threadIdx.x >> 6] = v;
    __syncthreads();
    if (threadIdx.x == 0) {
      float t = sl[0] + sl[1] + sl[2] + sl[3];
      if (t != 0.f) atomicAdd(pmsum, t);
    }
  }
  for (int i = threadIdx.x; i < NBUCK; i += 256) h[i] = 0;
  __syncthreads();
  int chunk = (E + NBLK - 1) / NBLK;
  int s = blockIdx.x * chunk;
  int e = min(E, s + chunk);
  for (int i = s + threadIdx.x; i < e; i += 256) atomicAdd(&h[cols[i] >> 8], 1);
  __syncthreads();
  for (int i = threadIdx.x; i < NBUCK; i += 256)
    histG[blockIdx.x * NBUCK + i] = h[i];
}

// ---------------- P2: scan of NBUCK*NBLK counts, bucket-major logical order ----------------

__global__ __launch_bounds__(256) void scan_partials_t(const int* __restrict__ histG,
                                                       int* __restrict__ partials,
                                                       int total, int NBUCK) {
  int i = blockIdx.x * 256 + threadIdx.x;
  int v = 0;
  if (i < total) {
    int bucket = i >> NBLK_SHIFT, blk = i & (NBLK - 1);
    v = histG[blk * NBUCK + bucket];
  }
#pragma unroll
  for (int o = 32; o > 0; o >>= 1) v += __shfl_down(v, o);
  __shared__ int s[4];
  if ((threadIdx.x & 63) == 0) s[threadIdx.x >> 6] = v;
  __syncthreads();
  if (threadIdx.x == 0) partials[blockIdx.x] = s[0] + s[1] + s[2] + s[3];
}

__global__ __launch_bounds__(256) void scan_block(int* __restrict__ partials, int nb,
                                                  float* __restrict__ loss) {
  __shared__ int tmp[256];
  __shared__ int carry;
  int tid = threadIdx.x;
  if (tid == 0) { carry = 0; *loss = 0.f; }
  __syncthreads();
  for (int base = 0; base < nb; base += 256) {
    int i = base + tid;
    int v = (i < nb) ? partials[i] : 0;
    tmp[tid] = v;
    __syncthreads();
    int incl = v;
    for (int o = 1; o < 256; o <<= 1) {
      int t = (tid >= o) ? tmp[tid - o] : 0;
      __syncthreads();
      incl += t;
      tmp[tid] = incl;
      __syncthreads();
    }
    int total = tmp[255];
    int c = carry;
    if (i < nb) partials[i] = c + incl - v;  // exclusive
    __syncthreads();
    if (tid == 0) carry = c + total;
    __syncthreads();
  }
}

__global__ __launch_bounds__(256) void scan_final_t(const int* __restrict__ histG,
                                                    const int* __restrict__ partials,
                                                    int* __restrict__ scannedG,
                                                    int total, int NBUCK) {
  __shared__ int tmp[256];
  int tid = threadIdx.x;
  int i = blockIdx.x * 256 + tid;
  int bucket = i >> NBLK_SHIFT, blk = i & (NBLK - 1);
  int v = (i < total) ? histG[blk * NBUCK + bucket] : 0;
  tmp[tid] = v;
  __syncthreads();
  int incl = v;
  for (int o = 1; o < 256; o <<= 1) {
    int t = (tid >= o) ? tmp[tid - o] : 0;
    __syncthreads();
    incl += t;
    tmp[tid] = incl;
    __syncthreads();
  }
  if (i < total) scannedG[blk * NBUCK + bucket] = partials[blockIdx.x] + incl - v;
}

// ---------------- P3: bucket-partition scatter (LDS cursors, no global atomics) ----------------

__global__ __launch_bounds__(256) void scatter_kernel(const int* __restrict__ rows,
                                                      const int* __restrict__ cols,
                                                      const int* __restrict__ scannedG,
                                                      unsigned int* __restrict__ packed,
                                                      int E, int NBUCK) {
  __shared__ int cur[512];
  for (int i = threadIdx.x; i < NBUCK; i += 256)
    cur[i] = scannedG[blockIdx.x * NBUCK + i];
  __syncthreads();
  int chunk = (E + NBLK - 1) / NBLK;
  int s = blockIdx.x * chunk;
  int e = min(E, s + chunk);
  for (int i = s + threadIdx.x; i < e; i += 256) {
    int c = cols[i];
    int r = rows[i];
    int pos = atomicAdd(&cur[c >> 8], 1);
    packed[pos] = ((unsigned int)(c & 255) << 24) | (unsigned int)r;
  }
}

// ---------------- P4: per-bucket CSR finalize (1024 threads/block) ----------------

__global__ __launch_bounds__(1024) void csr_finalize(const unsigned int* __restrict__ packed,
                                                     const int* __restrict__ scannedG,
                                                     int* __restrict__ sorted_src,
                                                     int* __restrict__ offsets,
                                                     float* __restrict__ dinv,
                                                     int N, int E, int NBUCK) {
  __shared__ int h[256];
  __shared__ int tmp[256];
  __shared__ int cur[256];
  int b = blockIdx.x;
  int tid = threadIdx.x;
  int base = scannedG[b];
  int end = (b + 1 < NBUCK) ? scannedG[b + 1] : E;
  if (tid < 256) h[tid] = 0;
  __syncthreads();
  for (int i = base + tid; i < end; i += 1024)
    atomicAdd(&h[packed[i] >> 24], 1);
  __syncthreads();
  if (tid < 256) {
    int v = h[tid];
    tmp[tid] = v;
  }
  __syncthreads();
  if (tid < 256) {
    int v = h[tid];
    int incl = v;
    for (int o = 1; o < 256; o <<= 1) {
      int t = (tid >= o) ? tmp[tid - o] : 0;
      __syncthreads();
      incl += t;
      tmp[tid] = incl;
      __syncthreads();
    }
    int excl = incl - v;
    int node = b * 256 + tid;
    if (node < N) {
      offsets[node] = base + excl;
      dinv[node] = rsqrtf((float)(v + 1));  // +1 self loop
    }
    cur[tid] = base + excl;
    if (b == NBUCK - 1 && tid == 0) offsets[N] = E;
  } else {
    for (int o = 1; o < 256; o <<= 1) { __syncthreads(); __syncthreads(); }
  }
  __syncthreads();
  for (int i = base + tid; i < end; i += 1024) {
    unsigned int p = packed[i];
    int pos = atomicAdd(&cur[p >> 24], 1);
    sorted_src[pos] = (int)(p & 0xFFFFFFu);
  }
}

// ---------------- MFMA GEMM: A_fp8[N,64] = (h[N,K] @ W[K,64]) * dinv[n] ----------------

template <int K, bool F32IN>
__global__ __launch_bounds__(256) void mfma_gemm(const void* __restrict__ hv,
                                                 const unsigned short* __restrict__ Wt,
                                                 const float* __restrict__ dinv,
                                                 unsigned char* __restrict__ out, int N) {
  __shared__ unsigned short tile[4][16 * 68];
  int w = threadIdx.x >> 6, lane = threadIdx.x & 63;
  int m = lane & 15, quad = lane >> 4;
  int m0 = blockIdx.x * 64 + w * 16;
  int rowA = m0 + m;
  bool rowOK = rowA < N;
  f32x4 acc[4] = {{0.f,0.f,0.f,0.f},{0.f,0.f,0.f,0.f},{0.f,0.f,0.f,0.f},{0.f,0.f,0.f,0.f}};
#pragma unroll
  for (int kc = 0; kc < K / 32; ++kc) {
    short8 a = {0, 0, 0, 0, 0, 0, 0, 0};
    if (rowOK) {
      if (F32IN) {
        const float* hp = (const float*)hv + (size_t)rowA * K + kc * 32 + quad * 8;
        float4 p0 = ((const float4*)hp)[0];
        float4 p1 = ((const float4*)hp)[1];
        a[0] = (short)f2bf(p0.x); a[1] = (short)f2bf(p0.y);
        a[2] = (short)f2bf(p0.z); a[3] = (short)f2bf(p0.w);
        a[4] = (short)f2bf(p1.x); a[5] = (short)f2bf(p1.y);
        a[6] = (short)f2bf(p1.z); a[7] = (short)f2bf(p1.w);
      } else {
        a = *(const short8*)((const unsigned short*)hv + (size_t)rowA * K + kc * 32 + quad * 8);
      }
    }
#pragma unroll
    for (int t = 0; t < 4; ++t) {
      short8 b = *(const short8*)(Wt + (size_t)(t * 16 + m) * K + kc * 32 + quad * 8);
      acc[t] = __builtin_amdgcn_mfma_f32_16x16x32_bf16(a, b, acc[t], 0, 0, 0);
    }
  }
  unsigned short* tw = tile[w];
#pragma unroll
  for (int r = 0; r < 4; ++r) {
    int row = quad * 4 + r;
    int gr = m0 + row;
    float dv = dinv[gr < N ? gr : 0];
#pragma unroll
    for (int t = 0; t < 4; ++t)
      tw[row * 68 + t * 16 + m] = f2bf(acc[t][r] * dv);
  }
#pragma unroll
  for (int p = 0; p < 4; ++p) {
    int row = p * 4 + (lane >> 4);
    int ch = lane & 15;  // 4-feature chunk
    int gr = m0 + row;
    if (gr < N) {
      uint2 v = *(const uint2*)(tw + row * 68 + ch * 4);
      float f0 = bf2f((unsigned short)(v.x & 0xFFFFu));
      float f1 = bf2f((unsigned short)(v.x >> 16));
      float f2 = bf2f((unsigned short)(v.y & 0xFFFFu));
      float f3 = bf2f((unsigned short)(v.y >> 16));
      int pk = 0;
      pk = __builtin_amdgcn_cvt_pk_fp8_f32(f0, f1, pk, false);
      pk = __builtin_amdgcn_cvt_pk_fp8_f32(f2, f3, pk, true);
      *(unsigned int*)(out + (size_t)gr * 64 + ch * 4) = (unsigned int)pk;
    }
  }
}

// ---------------- fused gather-aggregate + self loop + bias + ReLU ----------------
// A fp8 (64B rows). FOUR nodes per wave (16-lane quarters): 2 edge-groups x 8
// lanes, 8B/lane chunk. Avg degree ~16 -> 8 gathers in flight per quarter
// (32/wave, 2x the half-wave layout). fp32 accumulate; out H is bf16.

__global__ __launch_bounds__(256) void aggregate(const unsigned char* __restrict__ A8,
                                                 const int* __restrict__ offsets,
                                                 const int* __restrict__ sorted_src,
                                                 const float* __restrict__ dinv,
                                                 const float* __restrict__ bias,
                                                 unsigned short* __restrict__ out, int N) {
  int c = blockIdx.x * 16 + (threadIdx.x >> 4);  // one node per 16-lane quarter
  if (c >= N) return;
  int l = threadIdx.x & 15;
  int qbase = threadIdx.x & 48;      // quarter base lane within the wave
  int g = l >> 3;                    // edge sub-slot 0..1
  int fi = l & 7;                    // 8B chunk (8 feats) of the 64B row
  int s = offsets[c], e = offsets[c + 1];
  float dc = dinv[c];
  uint2 svr = *(const uint2*)(A8 + (size_t)c * 64 + fi * 8);
  f32x2 a0 = {0.f, 0.f}, a1 = {0.f, 0.f}, a2 = {0.f, 0.f}, a3 = {0.f, 0.f};
  for (int base = s; base < e; base += 16) {
    int idx = base + l;
    int r = (idx < e) ? sorted_src[idx] : 0;
    int cnt = e - base; if (cnt > 16) cnt = 16;
    int rj[8];
#pragma unroll
    for (int t = 0; t < 8; ++t) rj[t] = __shfl(r, qbase + t * 2 + g);
#pragma unroll
    for (int t = 0; t < 8; ++t) {
      if (t * 2 + g < cnt) {
        uint2 v = *(const uint2*)(A8 + ((size_t)(unsigned int)rj[t] << 6) + fi * 8);
        a0 += __builtin_amdgcn_cvt_pk_f32_fp8((int)v.x, false);
        a1 += __builtin_amdgcn_cvt_pk_f32_fp8((int)v.x, true);
        a2 += __builtin_amdgcn_cvt_pk_f32_fp8((int)v.y, false);
        a3 += __builtin_amdgcn_cvt_pk_f32_fp8((int)v.y, true);
      }
    }
  }
  float acc[8] = {a0[0], a0[1], a1[0], a1[1], a2[0], a2[1], a3[0], a3[1]};
#pragma unroll
  for (int q = 0; q < 8; ++q)          // reduce the 2 groups (stay within quarter)
    acc[q] += __shfl_xor(acc[q], 8);
  if (g == 0) {                        // lanes fi=0..7 of each quarter
    f32x2 s0 = __builtin_amdgcn_cvt_pk_f32_fp8((int)svr.x, false);
    f32x2 s1 = __builtin_amdgcn_cvt_pk_f32_fp8((int)svr.x, true);
    f32x2 s2 = __builtin_amdgcn_cvt_pk_f32_fp8((int)svr.y, false);
    f32x2 s3 = __builtin_amdgcn_cvt_pk_f32_fp8((int)svr.y, true);
    float sf[8] = {s0[0], s0[1], s1[0], s1[1], s2[0], s2[1], s3[0], s3[1]};
    short8 ov;
#pragma unroll
    for (int q = 0; q < 8; ++q) {
      float v = fmaf(acc[q] + sf[q], dc, bias[fi * 8 + q]);
      ov[q] = (short)f2bf(v > 0.f ? v : 0.f);
    }
    *(short8*)(out + (size_t)c * 64 + fi * 8) = ov;
  }
}

// ---------------- MLP head + sigmoid + weighted BCE loss (bf16 h) ----------------

__global__ __launch_bounds__(256) void head_loss_kernel(const unsigned short* __restrict__ h,
                                                        const float* __restrict__ lW1,
                                                        const float* __restrict__ lb1,
                                                        const float* __restrict__ lW2,
                                                        const float* __restrict__ lb2,
                                                        const int* __restrict__ labels,
                                                        const float* __restrict__ pmsum,
                                                        float* __restrict__ p,
                                                        float* __restrict__ loss, int N) {
  int n = blockIdx.x * 256 + threadIdx.x;
  float contrib = 0.f;
  if (n < N) {
    float acc[8];
#pragma unroll
    for (int j = 0; j < 8; ++j) acc[j] = lb1[j];
    const unsigned short* hr = h + (size_t)n * 64;
#pragma unroll
    for (int ch = 0; ch < 8; ++ch) {
      short8 hv8 = ((const short8*)hr)[ch];
#pragma unroll
      for (int q = 0; q < 8; ++q) {
        float v = bf2f((unsigned short)hv8[q]);
        int k = ch * 8 + q;
#pragma unroll
        for (int j = 0; j < 8; ++j) acc[j] = fmaf(v, lW1[k * 8 + j], acc[j]);
      }
    }
    float s = lb2[0];
#pragma unroll
    for (int j = 0; j < 8; ++j) {
      float a = acc[j] > 0.f ? acc[j] : 0.f;
      s = fmaf(a, lW2[j], s);
    }
    float pv = 1.0f / (1.0f + expf(-s));
    p[n] = pv;
    float pm = *pmsum / (float)N;
    float y = (float)labels[n];
    float w = y * (1.f - pm) + (1.f - y) * pm;
    float pc = fminf(fmaxf(pv, 1e-7f), 1.f - 1e-7f);
    float bce = -(y * logf(pc) + (1.f - y) * logf(1.f - pc));
    contrib = w * bce / (float)N;
  }
#pragma unroll
  for (int o = 32; o > 0; o >>= 1) contrib += __shfl_down(contrib, o);
  __shared__ float sh[4];
  int lane = threadIdx.x & 63, w = threadIdx.x >> 6;
  if (lane == 0) sh[w] = contrib;
  __syncthreads();
  if (threadIdx.x == 0) atomicAdd(loss, sh[0] + sh[1] + sh[2] + sh[3]);
}

// ---------------- launch ----------------

extern "C" void kernel_launch(void* const* d_in, const int* in_sizes, int n_in,
                              void* d_out, int out_size, void* d_ws, size_t ws_size,
                              hipStream_t stream) {
  const float* x      = (const float*)d_in[0];
  const int*   ei     = (const int*)d_in[1];
  const int*   labels = (const int*)d_in[2];
  const float* W1 = (const float*)d_in[3];
  const float* b1 = (const float*)d_in[4];
  const float* W2 = (const float*)d_in[5];
  const float* b2 = (const float*)d_in[6];
  const float* W3 = (const float*)d_in[7];
  const float* b3 = (const float*)d_in[8];
  const float* lW1 = (const float*)d_in[9];
  const float* lb1 = (const float*)d_in[10];
  const float* lW2 = (const float*)d_in[11];
  const float* lb2 = (const float*)d_in[12];

  int N = in_sizes[2];            // labels: [N,1]
  int E = in_sizes[1] / 2;        // edge_index: [2,E]
  const int* rows = ei;           // sources
  const int* cols = ei + E;       // targets (aggregation)

  int nb = (N + 255) / 256;
  int Npad = (N + 63) & ~63;
  int NBUCK = (N + 255) >> 8;               // 256-node buckets
  int totalH = NBUCK * NBLK;                // histogram entries
  int nb2 = (totalH + 255) / 256;

  // workspace layout
  char* ws = (char*)d_ws;
  unsigned char*  A8  = (unsigned char*)ws;             // (h@W)*dinv  Npad*64 fp8
  unsigned short* H   = (unsigned short*)(ws + (size_t)Npad * 64);  // hidden Npad*64 bf16
  unsigned short* Wt1 = H + (size_t)Npad * 64;          // 64*128
  unsigned short* Wt2 = Wt1 + 64 * 128;                 // 64*64
  unsigned short* Wt3 = Wt2 + 64 * 64;                  // 64*64
  float* dinv     = (float*)(Wt3 + 64 * 64);            // N
  int*   offsets  = (int*)(dinv + N);                   // N+1
  int*   histG    = offsets + N + 1;                    // NBLK*NBUCK
  int*   scanned  = histG + totalH;                     // NBLK*NBUCK
  unsigned int* packed = (unsigned int*)(scanned + totalH);  // E
  int*   sorted   = (int*)(packed + E);                 // E
  int*   partials = sorted + E;                         // nb2
  float* pmsum    = (float*)(partials + nb2);           // 1

  float* loss = (float*)d_out;
  float* p    = (float*)d_out + 1;

  int gemmBlocks = Npad / 64;
  int aggBlocks  = (N + 15) / 16;

  // ---- atomic-free CSR build (+ Wt transpose & label-sum folded into hist) ----
  hipMemsetAsync(pmsum, 0, sizeof(float), stream);
  hist_kernel<<<NBLK, 256, 0, stream>>>(cols, histG, labels, pmsum,
                                        W1, W2, W3, Wt1, Wt2, Wt3, E, N, NBUCK);
  scan_partials_t<<<nb2, 256, 0, stream>>>(histG, partials, totalH, NBUCK);
  scan_block<<<1, 256, 0, stream>>>(partials, nb2, loss);  // also zeroes loss
  scan_final_t<<<nb2, 256, 0, stream>>>(histG, partials, scanned, totalH, NBUCK);
  scatter_kernel<<<NBLK, 256, 0, stream>>>(rows, cols, scanned, packed, E, NBUCK);
  csr_finalize<<<NBUCK, 1024, 0, stream>>>(packed, scanned, sorted, offsets, dinv, N, E, NBUCK);

  // ---- layer 1 (K=128, fp32 x converted in-flight) ----
  mfma_gemm<128, true><<<gemmBlocks, 256, 0, stream>>>(x, Wt1, dinv, A8, N);
  aggregate<<<aggBlocks, 256, 0, stream>>>(A8, offsets, sorted, dinv, b1, H, N);

  // ---- layer 2 (K=64, bf16) ----
  mfma_gemm<64, false><<<gemmBlocks, 256, 0, stream>>>(H, Wt2, dinv, A8, N);
  aggregate<<<aggBlocks, 256, 0, stream>>>(A8, offsets, sorted, dinv, b2, H, N);

  // ---- layer 3 (K=64, bf16) ----
  mfma_gemm<64, false><<<gemmBlocks, 256, 0, stream>>>(H, Wt3, dinv, A8, N);
  aggregate<<<aggBlocks, 256, 0, stream>>>(A8, offsets, sorted, dinv, b3, H, N);

  // ---- head + loss ----
  head_loss_kernel<<<nb, 256, 0, stream>>>(H, lW1, lb1, lW2, lb2, labels, pmsum, p, loss, N);
}